// Round 6
// baseline (13368.460 us; speedup 1.0000x reference)
//
#include <hip/hip_runtime.h>

// OR_LSTM: 2-layer LSTM autoregressive rollout, wavefront-pipelined.
// B=32, T=128, D=16, H=256, WS=8, OUT=8. 120 windows over 127 iterations.
// Round 5: NO cache-maintenance ops in the loop (no threadfence, no
// acquire/release). All cross-wg state via RELAXED agent-scope atomics
// (MALL-coherent, L2-bypassing). c-state in registers. 16-wg group
// barriers (leader tree). Per-rt head (no pair scope). Weights L2-resident.

#define NWG 256
#define TPB 512

// ---- control region (u32 indices, zeroed by hipMemsetAsync) ----
#define ARR_U(rt, uc)  (((rt) * 16 + (uc)) * 16)          // arrival lines
#define RELB_U(rt, uc) (4096 + ((rt) * 16 + (uc)) * 16)   // release lines
#define RDYA_U(w)      (8192 + (w) * 16)                  // ready (even rt)
#define RDYB_U(w)      (12288 + (w) * 16)                 // ready (odd rt)
#define CTRL_BYTES     65536

// ---- float indices ----
#define H0A_F   16384
#define H0B_F   (H0A_F + 65536)
#define H1A_F   (H0B_F + 65536)
#define H1B_F   (H1A_F + 65536)
// packed weights: PW[uc][kb4][c][kk] (uc stride 16384 floats)
#define PWHH0_F (H1B_F + 65536)
#define PWIH1_F (PWHH0_F + 262144)
#define PWHH1_F (PWIH1_F + 262144)
#define PWIH0_F (PWHH1_F + 262144)   // [uc][k][c], k<16 (uc stride 1024)
// total 1081344 floats ~= 4.13 MiB

__device__ __forceinline__ float sigf(float x) { return 1.0f / (1.0f + __expf(-x)); }
__device__ __forceinline__ float tanhfast(float x) {
  float e = __expf(2.0f * x);
  return 1.0f - 2.0f / (e + 1.0f);
}

// Relaxed agent-scope atomics: MALL-coherent, NO buffer_inv / buffer_wbl2.
__device__ __forceinline__ unsigned rload(const unsigned* p) {
  return __hip_atomic_load(p, __ATOMIC_RELAXED, __HIP_MEMORY_SCOPE_AGENT);
}
__device__ __forceinline__ void rstore(unsigned* p, unsigned v) {
  __hip_atomic_store(p, v, __ATOMIC_RELAXED, __HIP_MEMORY_SCOPE_AGENT);
}
__device__ __forceinline__ float aload_f(const float* p) {
  union { unsigned u; float f; } cv;
  cv.u = __hip_atomic_load((const unsigned*)p, __ATOMIC_RELAXED,
                           __HIP_MEMORY_SCOPE_AGENT);
  return cv.f;
}
__device__ __forceinline__ void astore_f(float* p, float v) {
  union { float f; unsigned u; } cv;
  cv.f = v;
  __hip_atomic_store((unsigned*)p, cv.u, __ATOMIC_RELAXED,
                     __HIP_MEMORY_SCOPE_AGENT);
}
__device__ __forceinline__ float2 aload_f2(const float* p) {
  union { unsigned long long u; float2 f; } cv;
  cv.u = __hip_atomic_load((const unsigned long long*)p, __ATOMIC_RELAXED,
                           __HIP_MEMORY_SCOPE_AGENT);
  return cv.f;
}

// 16-wg group barrier, leader tree. Entry __syncthreads drains each wave's
// vmcnt (atomic data stores complete at MALL) before the arrival post.
__device__ __forceinline__ void groupbar16(unsigned* ctrl, int rt, int uc,
                                           unsigned seq) {
  __syncthreads();
  const int tid = threadIdx.x;
  if (uc == 0) {
    if (tid >= 1 && tid < 16) {
      const unsigned* a = &ctrl[ARR_U(rt, tid)];
      while (rload(a) < seq) __builtin_amdgcn_s_sleep(1);
      rstore(&ctrl[RELB_U(rt, tid)], seq);
    }
    __syncthreads();
  } else {
    if (tid == 0) {
      rstore(&ctrl[ARR_U(rt, uc)], seq);
      while (rload(&ctrl[RELB_U(rt, uc)]) < seq) __builtin_amdgcn_s_sleep(1);
    }
    __syncthreads();
  }
}

// Pack weights: PW[uc][kb4][c][kk] = W[j(c,uc)][kb4*4+kk].
__global__ __launch_bounds__(256) void lstm_prep(
    const float* __restrict__ Wih0, const float* __restrict__ Whh0,
    const float* __restrict__ Wih1, const float* __restrict__ Whh1,
    float* __restrict__ wsf) {
  const int i = blockIdx.x * 256 + threadIdx.x;
  if (i < 262144) {
    const int uc  = i >> 14;
    const int kb4 = (i >> 8) & 63;
    const int c   = (i >> 2) & 63;
    const int kk  = i & 3;
    const int k   = kb4 * 4 + kk;
    const int j   = (c >> 4) * 256 + uc * 16 + (c & 15);
    wsf[PWHH0_F + i] = Whh0[j * 256 + k];
    wsf[PWIH1_F + i] = Wih1[j * 256 + k];
    wsf[PWHH1_F + i] = Whh1[j * 256 + k];
    if (k < 16) wsf[PWIH0_F + uc * 1024 + k * 64 + c] = Wih0[j * 16 + k];
  }
}

__global__ __launch_bounds__(TPB, 2) void lstm_main(
    const float* __restrict__ traj,
    const float* __restrict__ bih0, const float* __restrict__ bhh0,
    const float* __restrict__ bih1, const float* __restrict__ bhh1,
    const float* __restrict__ Wlin, const float* __restrict__ blin,
    float* __restrict__ out, float* __restrict__ wsf) {
  __shared__ float big[8192];     // staging then partial planes
  __shared__ float sh_x[256];
  __shared__ float sh_g[1024];
  __shared__ float sh_o[128];
  __shared__ float sh_wfb[512];   // Wih0 feedback rows [d<8][c] (packed)
  __shared__ float sh_b0[64];     // bih0+bhh0 for this uc's 64 cols
  __shared__ float sh_b1[64];

  const int tid = threadIdx.x;
  const int wg  = blockIdx.x;
  const int rt  = wg >> 4;          // row tile (16 rows), 0..15
  const int uc  = wg & 15;          // unit chunk (16 hidden units)
  const int pair    = rt >> 1;      // pipeline slot 0..7
  const int rowBase = rt << 4;

  const int ks = tid >> 6;          // K-split 0..7 (wave id)
  const int c  = tid & 63;          // packed col 0..63

  unsigned* ctrl = (unsigned*)wsf;

  const float4* PW_hh0 = (const float4*)(wsf + PWHH0_F + uc * 16384);
  const float4* PW_ih1 = (const float4*)(wsf + PWIH1_F + uc * 16384);
  const float4* PW_hh1 = (const float4*)(wsf + PWHH1_F + uc * 16384);
  const float*  PW_ih0 = wsf + PWIH0_F + uc * 1024;

  // ---- one-time LDS prestage (iteration-invariant) ----
  sh_wfb[tid] = PW_ih0[(8 + (tid >> 6)) * 64 + (tid & 63)];
  if (tid < 64) {
    const int j = (tid >> 4) * 256 + uc * 16 + (tid & 15);
    sh_b0[tid] = bih0[j] + bhh0[j];
    sh_b1[tid] = bih1[j] + bhh1[j];
  }

  unsigned seq = 0;
  float acc1[16], acc2[16];
  float c0reg = 0.f, c1reg = 0.f;   // cell state in registers (tid<256)

  for (int g = 0; g < 127; ++g) {
    const int s = (g - pair) & 7;
    const int t = g - s;
    const bool valid = (t >= 0) && (t <= 119);
    const bool fresh = (s == 0) || (!valid);
    const int p = g & 1;

    // ============ PREWORK (ungated) ============
    if (tid < 256) {  // stage x: ctrl part (fb dims injected post-gate)
      const int r = tid >> 4, d = tid & 15;
      const int b = (rowBase + r) & 31;
      float xv = 0.0f;
      if (valid) {
        if (t <= 7 && s < 8 - t) {
          xv = traj[b * 2048 + (t + s) * 16 + d];   // raw window (g<8 only)
        } else if (d < 8) {
          const int ti = (t <= 7) ? (2 * t + s - 1) : (t + s);
          xv = traj[b * 2048 + ti * 16 + d];
        }
      }
      sh_x[tid] = xv;
    }
    {  // stage h0prev -> big[0:4096], h1prev -> big[4096:8192] (MALL loads)
      const float* h0r = wsf + (p ? H0B_F : H0A_F) + rowBase * 256;
      const float* h1r = wsf + (p ? H1B_F : H1A_F) + rowBase * 256;
      float2* B2 = (float2*)big;
      const float2 z = make_float2(0.f, 0.f);
#pragma unroll
      for (int i = 0; i < 4; ++i) {
        const int idx = tid + i * 512;
        B2[idx]        = fresh ? z : aload_f2(h0r + idx * 2);
        B2[2048 + idx] = fresh ? z : aload_f2(h1r + idx * 2);
      }
    }
    __syncthreads();

#pragma unroll
    for (int r = 0; r < 16; ++r) { acc1[r] = 0.f; acc2[r] = 0.f; }
    {  // bulk: Wih0·x_ctrl (K=16; fb dims zero here)
#pragma unroll
      for (int kk = 0; kk < 2; ++kk) {
        const int k = ks * 2 + kk;
        const float w = PW_ih0[k * 64 + c];
#pragma unroll
        for (int r = 0; r < 16; ++r)
          acc1[r] = fmaf(sh_x[r * 16 + k], w, acc1[r]);
      }
    }
    {  // bulk: Whh0·h0prev (acc1) + Whh1·h1prev (acc2), K=256
      const float4* A4 = (const float4*)big;
      const float4* B4 = A4 + 1024;
#pragma unroll
      for (int kc = 0; kc < 8; ++kc) {
        const int kb4 = ks * 8 + kc;
        const float4 wa = PW_hh0[kb4 * 64 + c];
        const float4 wb = PW_hh1[kb4 * 64 + c];
#pragma unroll
        for (int r = 0; r < 16; ++r) {
          const float4 a4 = A4[r * 64 + kb4];
          const float4 b4 = B4[r * 64 + kb4];
          acc1[r] = fmaf(a4.x, wa.x, acc1[r]);
          acc1[r] = fmaf(a4.y, wa.y, acc1[r]);
          acc1[r] = fmaf(a4.z, wa.z, acc1[r]);
          acc1[r] = fmaf(a4.w, wa.w, acc1[r]);
          acc2[r] = fmaf(b4.x, wb.x, acc2[r]);
          acc2[r] = fmaf(b4.y, wb.y, acc2[r]);
          acc2[r] = fmaf(b4.z, wb.z, acc2[r]);
          acc2[r] = fmaf(b4.w, wb.w, acc2[r]);
        }
      }
    }
    __syncthreads();  // staging dead -> big becomes partial planes
    {
#pragma unroll
      for (int r = 0; r < 16; ++r) big[ks * 1024 + r * 64 + c] = acc1[r];
    }

    // ============ OUT-COLUMN GATE ============
    if (g >= 8) {
      if (tid == 0) {
        const unsigned need = (unsigned)(g - 7);
        while (rload(&ctrl[RDYA_U(wg)]) < need) __builtin_amdgcn_s_sleep(1);
        while (rload(&ctrl[RDYB_U(wg)]) < need) __builtin_amdgcn_s_sleep(1);
      }
    }
    __syncthreads();  // also orders plane-writes vs reduce
    if (g >= 8 && tid < 128) {  // stage out[g-8] slice (MALL loads)
      const int rr = tid >> 3, d = tid & 7;
      const int b = (rowBase + rr) & 31;
      sh_o[tid] = aload_f(out + b * 960 + (g - 8) * 8 + d);
    }
    __syncthreads();
    {  // reduce + bias + rank-8 fb injection -> sh_g
      const bool inj = (g >= 8) && valid;
#pragma unroll
      for (int e = 0; e < 2; ++e) {
        const int oi = tid + e * 512;
        const int r = oi >> 6, lc = oi & 63;
        float sum = sh_b0[lc];
#pragma unroll
        for (int kq = 0; kq < 8; ++kq) sum += big[kq * 1024 + oi];
        if (inj) {
#pragma unroll
          for (int d = 0; d < 8; ++d)
            sum += sh_o[r * 8 + d] * sh_wfb[d * 64 + lc];
        }
        sh_g[oi] = sum;
      }
    }
    __syncthreads();
    if (tid < 256) {  // LSTM update, layer 0 (c in register)
      const int r = tid >> 4, u = tid & 15;
      const int grow = rowBase + r;
      const int gu = uc * 16 + u;
      const float iv = sh_g[r * 64 + u];
      const float fv = sh_g[r * 64 + 16 + u];
      const float gv = sh_g[r * 64 + 32 + u];
      const float ov = sh_g[r * 64 + 48 + u];
      const float cold = fresh ? 0.f : c0reg;
      const float cn = sigf(fv) * cold + sigf(iv) * tanhfast(gv);
      const float hn = sigf(ov) * tanhfast(cn);
      c0reg = cn;
      astore_f(wsf + (p ? H0A_F : H0B_F) + grow * 256 + gu, hn);
      if (g == 126 && rt >= 14) {  // h_n/c_n layer 0 (window 119 final)
        out[30720 + (grow - 224) * 256 + gu] = hn;
        out[47104 + (grow - 224) * 256 + gu] = cn;
      }
    }
    groupbar16(ctrl, rt, uc, ++seq);

    // ============ PHASE B (h0'-dependent) ============
    {  // stage h0' -> big[0:4096] (MALL loads)
      const float* h0w = wsf + (p ? H0A_F : H0B_F) + rowBase * 256;
      float2* B2 = (float2*)big;
#pragma unroll
      for (int i = 0; i < 4; ++i) {
        const int idx = tid + i * 512;
        B2[idx] = aload_f2(h0w + idx * 2);
      }
    }
    __syncthreads();
    {  // acc2 += Wih1·h0' (K=256)
      const float4* A4 = (const float4*)big;
#pragma unroll
      for (int kc = 0; kc < 8; ++kc) {
        const int kb4 = ks * 8 + kc;
        const float4 wa = PW_ih1[kb4 * 64 + c];
#pragma unroll
        for (int r = 0; r < 16; ++r) {
          const float4 a4 = A4[r * 64 + kb4];
          acc2[r] = fmaf(a4.x, wa.x, acc2[r]);
          acc2[r] = fmaf(a4.y, wa.y, acc2[r]);
          acc2[r] = fmaf(a4.z, wa.z, acc2[r]);
          acc2[r] = fmaf(a4.w, wa.w, acc2[r]);
        }
      }
    }
    __syncthreads();
    {
#pragma unroll
      for (int r = 0; r < 16; ++r) big[ks * 1024 + r * 64 + c] = acc2[r];
    }
    __syncthreads();
    {  // reduce + bias -> sh_g
#pragma unroll
      for (int e = 0; e < 2; ++e) {
        const int oi = tid + e * 512;
        float sum = sh_b1[oi & 63];
#pragma unroll
        for (int kq = 0; kq < 8; ++kq) sum += big[kq * 1024 + oi];
        sh_g[oi] = sum;
      }
    }
    __syncthreads();
    if (tid < 256) {  // LSTM update, layer 1
      const int r = tid >> 4, u = tid & 15;
      const int grow = rowBase + r;
      const int gu = uc * 16 + u;
      const float iv = sh_g[r * 64 + u];
      const float fv = sh_g[r * 64 + 16 + u];
      const float gv = sh_g[r * 64 + 32 + u];
      const float ov = sh_g[r * 64 + 48 + u];
      const float cold = fresh ? 0.f : c1reg;
      const float cn = sigf(fv) * cold + sigf(iv) * tanhfast(gv);
      const float hn = sigf(ov) * tanhfast(cn);
      c1reg = cn;
      astore_f(wsf + (p ? H1A_F : H1B_F) + grow * 256 + gu, hn);
      if (g == 126 && rt >= 14) {  // h_n/c_n layer 1
        out[30720 + 8192 + (grow - 224) * 256 + gu] = hn;
        out[47104 + 8192 + (grow - 224) * 256 + gu] = cn;
      }
    }
    groupbar16(ctrl, rt, uc, ++seq);

    // ============ HEAD (uc15 wg of each finishing rt) ============
    {
      const int tf = g - 7;
      if (tf >= 0 && uc == 15 && pair == (tf & 7)) {
        const int q = tid >> 7, idx = tid & 127;
        const int r = idx >> 3, o = idx & 7;
        const float* h1 =
            wsf + (p ? H1A_F : H1B_F) + (rowBase + r) * 256 + q * 64;
        const float2* wl2 = (const float2*)(Wlin + o * 256 + q * 64);
        float sum = 0.f;
#pragma unroll 8
        for (int k2 = 0; k2 < 32; ++k2) {
          const float2 h = aload_f2(h1 + k2 * 2);
          const float2 w = wl2[k2];
          sum = fmaf(h.x, w.x, sum);
          sum = fmaf(h.y, w.y, sum);
        }
        sh_g[q * 128 + idx] = sum;
        __syncthreads();
        if (tid < 128) {
          const int b = (rowBase + (tid >> 3)) & 31;
          const int oo = tid & 7;
          const float pred =
              sh_g[tid] + sh_g[128 + tid] + sh_g[256 + tid] + sh_g[384 + tid] +
              blin[oo];
          const float base = (tf == 0)
                                 ? traj[b * 2048 + 7 * 16 + 8 + oo]
                                 : aload_f(out + b * 960 + (tf - 1) * 8 + oo);
          astore_f(out + b * 960 + tf * 8 + oo, base + pred);
        }
        __syncthreads();  // drains out stores (vmcnt) before RDY posts
        if (tid < 256) {
          if ((rt & 1) == 0) rstore(&ctrl[RDYA_U(tid)], (unsigned)(tf + 1));
          else               rstore(&ctrl[RDYB_U(tid)], (unsigned)(tf + 1));
        }
      }
    }
  }
}

extern "C" void kernel_launch(void* const* d_in, const int* in_sizes, int n_in,
                              void* d_out, int out_size, void* d_ws, size_t ws_size,
                              hipStream_t stream) {
  (void)in_sizes; (void)n_in; (void)out_size; (void)ws_size;
  const float* traj = (const float*)d_in[0];
  const float* Wih0 = (const float*)d_in[1];
  const float* Whh0 = (const float*)d_in[2];
  const float* bih0 = (const float*)d_in[3];
  const float* bhh0 = (const float*)d_in[4];
  const float* Wih1 = (const float*)d_in[5];
  const float* Whh1 = (const float*)d_in[6];
  const float* bih1 = (const float*)d_in[7];
  const float* bhh1 = (const float*)d_in[8];
  const float* Wlin = (const float*)d_in[9];
  const float* blin = (const float*)d_in[10];
  float* out = (float*)d_out;
  float* wsf = (float*)d_ws;

  hipMemsetAsync(d_ws, 0, CTRL_BYTES, stream);
  lstm_prep<<<1024, 256, 0, stream>>>(Wih0, Whh0, Wih1, Whh1, wsf);

  void* args[] = {(void*)&traj, (void*)&bih0, (void*)&bhh0, (void*)&bih1,
                  (void*)&bhh1, (void*)&Wlin, (void*)&blin, (void*)&out,
                  (void*)&wsf};
  hipLaunchCooperativeKernel((void*)lstm_main, dim3(NWG), dim3(TPB), args, 0,
                             stream);
}

// Round 7
// 12178.589 us; speedup vs baseline: 1.0977x; 1.0977x over previous
//
#include <hip/hip_runtime.h>

// OR_LSTM: 2-layer LSTM autoregressive rollout, wavefront-pipelined.
// B=32, T=128, D=16, H=256, WS=8, OUT=8. 120 windows over 127 iterations.
// Round 6: bulk cross-wg data moves via PLAIN global dwordx4 loads/stores
// with sc0 sc1 (L1/L2-bypass, MALL-coherent, coalesced) — NOT atomics
// (atomics proved to be per-op uncoalesced fabric transactions: 20 GB of
// write traffic in rounds 4/5). Flags stay as relaxed agent atomics.
// Explicit s_waitcnt vmcnt(0) before every flag post = release.

#define NWG 256
#define TPB 512

typedef float f32x4 __attribute__((ext_vector_type(4)));

// ---- control region (u32 indices, zeroed by hipMemsetAsync) ----
#define ARR_U(rt, uc)  (((rt) * 16 + (uc)) * 16)          // arrival lines
#define RELB_U(rt, uc) (4096 + ((rt) * 16 + (uc)) * 16)   // release lines
#define RDYA_U(w)      (8192 + (w) * 16)                  // ready (even rt)
#define RDYB_U(w)      (12288 + (w) * 16)                 // ready (odd rt)
#define CTRL_BYTES     65536

// ---- float indices ----
#define H0A_F   16384
#define H0B_F   (H0A_F + 65536)
#define H1A_F   (H0B_F + 65536)
#define H1B_F   (H1A_F + 65536)
// packed weights: PW[uc][kb4][c][kk] (uc stride 16384 floats)
#define PWHH0_F (H1B_F + 65536)
#define PWIH1_F (PWHH0_F + 262144)
#define PWHH1_F (PWIH1_F + 262144)
#define PWIH0_F (PWHH1_F + 262144)   // [uc][k][c], k<16 (uc stride 1024)

__device__ __forceinline__ float sigf(float x) { return 1.0f / (1.0f + __expf(-x)); }
__device__ __forceinline__ float tanhfast(float x) {
  float e = __expf(2.0f * x);
  return 1.0f - 2.0f / (e + 1.0f);
}

// ---- flags: relaxed agent atomics (tiny volume) ----
__device__ __forceinline__ unsigned rload(const unsigned* p) {
  return __hip_atomic_load(p, __ATOMIC_RELAXED, __HIP_MEMORY_SCOPE_AGENT);
}
__device__ __forceinline__ void rstore(unsigned* p, unsigned v) {
  __hip_atomic_store(p, v, __ATOMIC_RELAXED, __HIP_MEMORY_SCOPE_AGENT);
}

// ---- bulk data: plain sc0|sc1 (L1/L2-bypass, MALL point of coherence) ----
__device__ __forceinline__ f32x4 mall_load_f4(const float* p) {
  f32x4 v;
  asm volatile("global_load_dwordx4 %0, %1, off sc0 sc1" : "=v"(v) : "v"(p));
  return v;
}
__device__ __forceinline__ void mall_store_f4(float* p, f32x4 v) {
  asm volatile("global_store_dwordx4 %0, %1, off sc0 sc1"
               :: "v"(p), "v"(v) : "memory");
}
__device__ __forceinline__ void mall_store_f(float* p, float v) {
  asm volatile("global_store_dword %0, %1, off sc0 sc1"
               :: "v"(p), "v"(v) : "memory");
}
__device__ __forceinline__ void vmdrain() {
  asm volatile("s_waitcnt vmcnt(0)" ::: "memory");
}
__device__ __forceinline__ void vmwait1(f32x4& a) {
  asm volatile("s_waitcnt vmcnt(0)" : "+v"(a) :: "memory");
}
__device__ __forceinline__ void vmwait3(f32x4& a, f32x4& b, f32x4& c) {
  asm volatile("s_waitcnt vmcnt(0)" : "+v"(a), "+v"(b), "+v"(c) :: "memory");
}
__device__ __forceinline__ void vmwait4(f32x4& a, f32x4& b, f32x4& c, f32x4& d) {
  asm volatile("s_waitcnt vmcnt(0)"
               : "+v"(a), "+v"(b), "+v"(c), "+v"(d) :: "memory");
}

// 16-wg group barrier, leader tree. vmdrain = release (sc1 stores at MALL).
__device__ __forceinline__ void groupbar16(unsigned* ctrl, int rt, int uc,
                                           unsigned seq) {
  vmdrain();
  __syncthreads();
  const int tid = threadIdx.x;
  if (uc == 0) {
    if (tid >= 1 && tid < 16) {
      const unsigned* a = &ctrl[ARR_U(rt, tid)];
      while (rload(a) < seq) __builtin_amdgcn_s_sleep(1);
      rstore(&ctrl[RELB_U(rt, tid)], seq);
    }
    __syncthreads();
  } else {
    if (tid == 0) {
      rstore(&ctrl[ARR_U(rt, uc)], seq);
      while (rload(&ctrl[RELB_U(rt, uc)]) < seq) __builtin_amdgcn_s_sleep(1);
    }
    __syncthreads();
  }
}

// Pack weights: PW[uc][kb4][c][kk] = W[j(c,uc)][kb4*4+kk].
__global__ __launch_bounds__(256) void lstm_prep(
    const float* __restrict__ Wih0, const float* __restrict__ Whh0,
    const float* __restrict__ Wih1, const float* __restrict__ Whh1,
    float* __restrict__ wsf) {
  const int i = blockIdx.x * 256 + threadIdx.x;
  if (i < 262144) {
    const int uc  = i >> 14;
    const int kb4 = (i >> 8) & 63;
    const int c   = (i >> 2) & 63;
    const int kk  = i & 3;
    const int k   = kb4 * 4 + kk;
    const int j   = (c >> 4) * 256 + uc * 16 + (c & 15);
    wsf[PWHH0_F + i] = Whh0[j * 256 + k];
    wsf[PWIH1_F + i] = Wih1[j * 256 + k];
    wsf[PWHH1_F + i] = Whh1[j * 256 + k];
    if (k < 16) wsf[PWIH0_F + uc * 1024 + k * 64 + c] = Wih0[j * 16 + k];
  }
}

__global__ __launch_bounds__(TPB) void lstm_main(
    const float* __restrict__ traj,
    const float* __restrict__ bih0, const float* __restrict__ bhh0,
    const float* __restrict__ bih1, const float* __restrict__ bhh1,
    const float* __restrict__ Wlin, const float* __restrict__ blin,
    float* __restrict__ out, float* __restrict__ wsf) {
  __shared__ float big[8192];     // staging then partial planes / head h1
  __shared__ float sh_x[256];
  __shared__ float sh_g[1024];
  __shared__ float sh_o[128];
  __shared__ float sh_wfb[512];   // Wih0 feedback rows [d<8][c] (packed)
  __shared__ float sh_b0[64];
  __shared__ float sh_b1[64];
  __shared__ float sh_blin[8];

  const int tid = threadIdx.x;
  const int wg  = blockIdx.x;
  const int rt  = wg >> 4;          // row tile (16 rows), 0..15
  const int uc  = wg & 15;          // unit chunk (16 hidden units)
  const int pair    = rt >> 1;      // pipeline slot 0..7
  const int rowBase = rt << 4;

  const int ks = tid >> 6;          // K-split 0..7 (wave id)
  const int c  = tid & 63;          // packed col 0..63

  unsigned* ctrl = (unsigned*)wsf;

  const float4* PW_hh0 = (const float4*)(wsf + PWHH0_F + uc * 16384);
  const float4* PW_ih1 = (const float4*)(wsf + PWIH1_F + uc * 16384);
  const float4* PW_hh1 = (const float4*)(wsf + PWHH1_F + uc * 16384);
  const float*  PW_ih0 = wsf + PWIH0_F + uc * 1024;

  // ---- one-time LDS prestage (iteration-invariant) ----
  sh_wfb[tid] = PW_ih0[(8 + (tid >> 6)) * 64 + (tid & 63)];
  if (tid < 64) {
    const int j = (tid >> 4) * 256 + uc * 16 + (tid & 15);
    sh_b0[tid] = bih0[j] + bhh0[j];
    sh_b1[tid] = bih1[j] + bhh1[j];
  }
  if (tid < 8) sh_blin[tid] = blin[tid];

  unsigned seq = 0;
  float acc1[16], acc2[16];
  float c0reg = 0.f, c1reg = 0.f;   // cell state in registers (tid<256)

  for (int g = 0; g < 127; ++g) {
    const int s = (g - pair) & 7;
    const int t = g - s;
    const bool valid = (t >= 0) && (t <= 119);
    const bool fresh = (s == 0) || (!valid);
    const int p = g & 1;

    // ============ PREWORK (ungated) ============
    if (tid < 256) {  // stage x: ctrl part (fb dims injected post-gate)
      const int r = tid >> 4, d = tid & 15;
      const int b = (rowBase + r) & 31;
      float xv = 0.0f;
      if (valid) {
        if (t <= 7 && s < 8 - t) {
          xv = traj[b * 2048 + (t + s) * 16 + d];   // raw window (g<8 only)
        } else if (d < 8) {
          const int ti = (t <= 7) ? (2 * t + s - 1) : (t + s);
          xv = traj[b * 2048 + ti * 16 + d];
        }
      }
      sh_x[tid] = xv;
    }
    {  // stage h0prev -> big[0:4096], h1prev -> big[4096:8192] (MALL, 16B)
      f32x4* B4 = (f32x4*)big;
      if (!fresh) {
        const float* h0r = wsf + (p ? H0B_F : H0A_F) + rowBase * 256;
        const float* h1r = wsf + (p ? H1B_F : H1A_F) + rowBase * 256;
        f32x4 a0 = mall_load_f4(h0r + tid * 4);
        f32x4 a1 = mall_load_f4(h0r + (tid + 512) * 4);
        f32x4 b0 = mall_load_f4(h1r + tid * 4);
        f32x4 b1 = mall_load_f4(h1r + (tid + 512) * 4);
        vmwait4(a0, a1, b0, b1);
        B4[tid] = a0; B4[tid + 512] = a1;
        B4[1024 + tid] = b0; B4[1536 + tid] = b1;
      } else {
        const f32x4 z = {0.f, 0.f, 0.f, 0.f};
        B4[tid] = z; B4[tid + 512] = z;
        B4[1024 + tid] = z; B4[1536 + tid] = z;
      }
    }
    __syncthreads();

#pragma unroll
    for (int r = 0; r < 16; ++r) { acc1[r] = 0.f; acc2[r] = 0.f; }
    {  // bulk: Wih0·x_ctrl (K=16; fb dims zero here)
#pragma unroll
      for (int kk = 0; kk < 2; ++kk) {
        const int k = ks * 2 + kk;
        const float w = PW_ih0[k * 64 + c];
#pragma unroll
        for (int r = 0; r < 16; ++r)
          acc1[r] = fmaf(sh_x[r * 16 + k], w, acc1[r]);
      }
    }
    {  // bulk: Whh0·h0prev (acc1) + Whh1·h1prev (acc2), K=256
      const float4* A4 = (const float4*)big;
      const float4* B4 = A4 + 1024;
#pragma unroll
      for (int kc = 0; kc < 8; ++kc) {
        const int kb4 = ks * 8 + kc;
        const float4 wa = PW_hh0[kb4 * 64 + c];
        const float4 wb = PW_hh1[kb4 * 64 + c];
#pragma unroll
        for (int r = 0; r < 16; ++r) {
          const float4 a4 = A4[r * 64 + kb4];
          const float4 b4 = B4[r * 64 + kb4];
          acc1[r] = fmaf(a4.x, wa.x, acc1[r]);
          acc1[r] = fmaf(a4.y, wa.y, acc1[r]);
          acc1[r] = fmaf(a4.z, wa.z, acc1[r]);
          acc1[r] = fmaf(a4.w, wa.w, acc1[r]);
          acc2[r] = fmaf(b4.x, wb.x, acc2[r]);
          acc2[r] = fmaf(b4.y, wb.y, acc2[r]);
          acc2[r] = fmaf(b4.z, wb.z, acc2[r]);
          acc2[r] = fmaf(b4.w, wb.w, acc2[r]);
        }
      }
    }
    __syncthreads();  // staging dead -> big becomes partial planes
    {
#pragma unroll
      for (int r = 0; r < 16; ++r) big[ks * 1024 + r * 64 + c] = acc1[r];
    }

    // ============ OUT-COLUMN GATE ============
    if (g >= 8) {
      if (tid == 0) {
        const unsigned need = (unsigned)(g - 7);
        while (rload(&ctrl[RDYA_U(wg)]) < need) __builtin_amdgcn_s_sleep(1);
        while (rload(&ctrl[RDYB_U(wg)]) < need) __builtin_amdgcn_s_sleep(1);
      }
    }
    __syncthreads();  // also orders plane-writes vs reduce
    if (g >= 8 && tid < 32) {  // stage out[g-8] slice (MALL, 16B)
      const int rr = tid >> 1, half = tid & 1;
      const int b = (rowBase + rr) & 31;
      f32x4 v = mall_load_f4(out + b * 960 + (g - 8) * 8 + half * 4);
      vmwait1(v);
      ((f32x4*)sh_o)[tid] = v;
    }
    __syncthreads();
    {  // reduce + bias + rank-8 fb injection -> sh_g
      const bool inj = (g >= 8) && valid;
#pragma unroll
      for (int e = 0; e < 2; ++e) {
        const int oi = tid + e * 512;
        const int r = oi >> 6, lc = oi & 63;
        float sum = sh_b0[lc];
#pragma unroll
        for (int kq = 0; kq < 8; ++kq) sum += big[kq * 1024 + oi];
        if (inj) {
#pragma unroll
          for (int d = 0; d < 8; ++d)
            sum += sh_o[r * 8 + d] * sh_wfb[d * 64 + lc];
        }
        sh_g[oi] = sum;
      }
    }
    __syncthreads();
    if (tid < 256) {  // LSTM update, layer 0 (c in register)
      const int r = tid >> 4, u = tid & 15;
      const int grow = rowBase + r;
      const int gu = uc * 16 + u;
      const float iv = sh_g[r * 64 + u];
      const float fv = sh_g[r * 64 + 16 + u];
      const float gv = sh_g[r * 64 + 32 + u];
      const float ov = sh_g[r * 64 + 48 + u];
      const float cold = fresh ? 0.f : c0reg;
      const float cn = sigf(fv) * cold + sigf(iv) * tanhfast(gv);
      const float hn = sigf(ov) * tanhfast(cn);
      c0reg = cn;
      mall_store_f(wsf + (p ? H0A_F : H0B_F) + grow * 256 + gu, hn);
      if (g == 126 && rt >= 14) {  // h_n/c_n layer 0 (window 119 final)
        out[30720 + (grow - 224) * 256 + gu] = hn;
        out[47104 + (grow - 224) * 256 + gu] = cn;
      }
    }
    groupbar16(ctrl, rt, uc, ++seq);

    // ============ PHASE B (h0'-dependent) ============
    {  // stage h0' -> big[0:4096] (MALL, 16B)
      const float* h0w = wsf + (p ? H0A_F : H0B_F) + rowBase * 256;
      f32x4 a0 = mall_load_f4(h0w + tid * 4);
      f32x4 a1 = mall_load_f4(h0w + (tid + 512) * 4);
      f32x4 dummy = a0;
      vmwait3(a0, a1, dummy);
      f32x4* B4 = (f32x4*)big;
      B4[tid] = a0; B4[tid + 512] = a1;
    }
    __syncthreads();
    {  // acc2 += Wih1·h0' (K=256)
      const float4* A4 = (const float4*)big;
#pragma unroll
      for (int kc = 0; kc < 8; ++kc) {
        const int kb4 = ks * 8 + kc;
        const float4 wa = PW_ih1[kb4 * 64 + c];
#pragma unroll
        for (int r = 0; r < 16; ++r) {
          const float4 a4 = A4[r * 64 + kb4];
          acc2[r] = fmaf(a4.x, wa.x, acc2[r]);
          acc2[r] = fmaf(a4.y, wa.y, acc2[r]);
          acc2[r] = fmaf(a4.z, wa.z, acc2[r]);
          acc2[r] = fmaf(a4.w, wa.w, acc2[r]);
        }
      }
    }
    __syncthreads();
    {
#pragma unroll
      for (int r = 0; r < 16; ++r) big[ks * 1024 + r * 64 + c] = acc2[r];
    }
    __syncthreads();
    {  // reduce + bias -> sh_g
#pragma unroll
      for (int e = 0; e < 2; ++e) {
        const int oi = tid + e * 512;
        float sum = sh_b1[oi & 63];
#pragma unroll
        for (int kq = 0; kq < 8; ++kq) sum += big[kq * 1024 + oi];
        sh_g[oi] = sum;
      }
    }
    __syncthreads();
    if (tid < 256) {  // LSTM update, layer 1
      const int r = tid >> 4, u = tid & 15;
      const int grow = rowBase + r;
      const int gu = uc * 16 + u;
      const float iv = sh_g[r * 64 + u];
      const float fv = sh_g[r * 64 + 16 + u];
      const float gv = sh_g[r * 64 + 32 + u];
      const float ov = sh_g[r * 64 + 48 + u];
      const float cold = fresh ? 0.f : c1reg;
      const float cn = sigf(fv) * cold + sigf(iv) * tanhfast(gv);
      const float hn = sigf(ov) * tanhfast(cn);
      c1reg = cn;
      mall_store_f(wsf + (p ? H1A_F : H1B_F) + grow * 256 + gu, hn);
      if (g == 126 && rt >= 14) {  // h_n/c_n layer 1
        out[30720 + 8192 + (grow - 224) * 256 + gu] = hn;
        out[47104 + 8192 + (grow - 224) * 256 + gu] = cn;
      }
    }
    groupbar16(ctrl, rt, uc, ++seq);

    // ============ HEAD (uc15 wg of each finishing rt) ============
    {
      const int tf = g - 7;
      if (tf >= 0 && uc == 15 && pair == (tf & 7)) {
        {  // stage this rt's h1' (16x256) -> big, base column -> sh_o
          const float* h1t = wsf + (p ? H1A_F : H1B_F) + rowBase * 256;
          f32x4 v0 = mall_load_f4(h1t + tid * 4);
          f32x4 v1 = mall_load_f4(h1t + (tid + 512) * 4);
          f32x4 vb = {0.f, 0.f, 0.f, 0.f};
          if (tid < 32) {
            const int bb = (rowBase + (tid >> 1)) & 31, half = tid & 1;
            if (tf == 0) {
              vb = *(const f32x4*)(traj + bb * 2048 + 7 * 16 + 8 + half * 4);
            } else {
              vb = mall_load_f4(out + bb * 960 + (tf - 1) * 8 + half * 4);
            }
          }
          vmwait3(v0, v1, vb);
          f32x4* B4 = (f32x4*)big;
          B4[tid] = v0; B4[tid + 512] = v1;
          if (tid < 32) ((f32x4*)sh_o)[tid] = vb;
        }
        __syncthreads();
        {  // partial dot: q-split 4 over K=256
          const int q = tid >> 7, idx = tid & 127;
          const int r = idx >> 3, o = idx & 7;
          const f32x4* hb = (const f32x4*)(big + r * 256 + q * 64);
          const f32x4* wb = (const f32x4*)(Wlin + o * 256 + q * 64);
          float sum = 0.f;
#pragma unroll 8
          for (int k4 = 0; k4 < 16; ++k4) {
            const f32x4 h = hb[k4];
            const f32x4 w = wb[k4];
            sum = fmaf(h.x, w.x, sum);
            sum = fmaf(h.y, w.y, sum);
            sum = fmaf(h.z, w.z, sum);
            sum = fmaf(h.w, w.w, sum);
          }
          sh_g[q * 128 + idx] = sum;
        }
        __syncthreads();
        if (tid < 32) {  // combine + store out column (16B)
          const int r = tid >> 1, half = tid & 1;
          const int b = (rowBase + r) & 31;
          f32x4 res;
#pragma unroll
          for (int j = 0; j < 4; ++j) {
            const int o = half * 4 + j;
            const int idx = r * 8 + o;
            res[j] = sh_o[r * 8 + o] + sh_blin[o] + sh_g[idx] +
                     sh_g[128 + idx] + sh_g[256 + idx] + sh_g[384 + idx];
          }
          mall_store_f4(out + b * 960 + tf * 8 + half * 4, res);
        }
        vmdrain();
        __syncthreads();  // out stores at MALL before RDY posts
        if (tid < 256) {
          if ((rt & 1) == 0) rstore(&ctrl[RDYA_U(tid)], (unsigned)(tf + 1));
          else               rstore(&ctrl[RDYB_U(tid)], (unsigned)(tf + 1));
        }
      }
    }
  }
}

extern "C" void kernel_launch(void* const* d_in, const int* in_sizes, int n_in,
                              void* d_out, int out_size, void* d_ws, size_t ws_size,
                              hipStream_t stream) {
  (void)in_sizes; (void)n_in; (void)out_size; (void)ws_size;
  const float* traj = (const float*)d_in[0];
  const float* Wih0 = (const float*)d_in[1];
  const float* Whh0 = (const float*)d_in[2];
  const float* bih0 = (const float*)d_in[3];
  const float* bhh0 = (const float*)d_in[4];
  const float* Wih1 = (const float*)d_in[5];
  const float* Whh1 = (const float*)d_in[6];
  const float* bih1 = (const float*)d_in[7];
  const float* bhh1 = (const float*)d_in[8];
  const float* Wlin = (const float*)d_in[9];
  const float* blin = (const float*)d_in[10];
  float* out = (float*)d_out;
  float* wsf = (float*)d_ws;

  hipMemsetAsync(d_ws, 0, CTRL_BYTES, stream);
  lstm_prep<<<1024, 256, 0, stream>>>(Wih0, Whh0, Wih1, Whh1, wsf);

  void* args[] = {(void*)&traj, (void*)&bih0, (void*)&bhh0, (void*)&bih1,
                  (void*)&bhh1, (void*)&Wlin, (void*)&blin, (void*)&out,
                  (void*)&wsf};
  hipLaunchCooperativeKernel((void*)lstm_main, dim3(NWG), dim3(TPB), args, 0,
                             stream);
}

// Round 9
// 4239.297 us; speedup vs baseline: 3.1535x; 2.8728x over previous
//
#include <hip/hip_runtime.h>

// OR_LSTM: 2-layer LSTM autoregressive rollout, wavefront-pipelined.
// B=32, T=128, D=16, H=256, WS=8, OUT=8. 120 windows over 127 iterations.
// Round 8: ROW-SPLIT, communication-free. 8 slots x 8 wgs x 4 batch rows.
// Each wg owns ALL 1024 gate cols for its rows -> h/c state is wg-private
// (LDS + registers). ZERO barriers. Only cross-wg traffic: 32 floats of
// out[:,g-8] + 1 RDY flag per wg per iter (R6-proven MALL primitives).
// Cost: weights (3.14 MB packed fp32) re-streamed from L2 every iteration.

#define NWG 64
#define TPB 512

typedef float f32x4 __attribute__((ext_vector_type(4)));

// ---- control region (u32 indices, zeroed by hipMemsetAsync) ----
#define RDY_U(rq, sl) (((rq) * 8 + (sl)) * 16)   // 64 ready lines, 1 poller each
#define CTRL_BYTES 4096

// ---- float indices in ws ----
#define PW0_F  2048                    // [68][1024][4]  k = x(16) then h0(256)
#define PW1A_F (PW0_F + 278528)        // [64][1024][4]  Wih1 (k = h0')
#define PW1B_F (PW1A_F + 262144)       // [64][1024][4]  Whh1 (k = h1)

__device__ __forceinline__ float sigf(float x) { return 1.0f / (1.0f + __expf(-x)); }
__device__ __forceinline__ float tanhfast(float x) {
  float e = __expf(2.0f * x);
  return 1.0f - 2.0f / (e + 1.0f);
}

// flags: relaxed agent atomics (R4-R6 proven coherent)
__device__ __forceinline__ unsigned rload(const unsigned* p) {
  return __hip_atomic_load(p, __ATOMIC_RELAXED, __HIP_MEMORY_SCOPE_AGENT);
}
__device__ __forceinline__ void rstore(unsigned* p, unsigned v) {
  __hip_atomic_store(p, v, __ATOMIC_RELAXED, __HIP_MEMORY_SCOPE_AGENT);
}
// tiny cross-wg data: MALL bypass dword ops (R6-proven)
__device__ __forceinline__ float mall_load_f(const float* p) {
  float v;
  asm volatile("global_load_dword %0, %1, off sc0 sc1\n\ts_waitcnt vmcnt(0)"
               : "=v"(v) : "v"(p) : "memory");
  return v;
}
__device__ __forceinline__ void mall_store_f(float* p, float v) {
  asm volatile("global_store_dword %0, %1, off sc0 sc1"
               :: "v"(p), "v"(v) : "memory");
}
__device__ __forceinline__ void vmdrain() {
  asm volatile("s_waitcnt vmcnt(0)" ::: "memory");
}

// Pack weights k-inner-4: PW[kb4][j][kk].
__global__ __launch_bounds__(256) void lstm_prep(
    const float* __restrict__ Wih0, const float* __restrict__ Whh0,
    const float* __restrict__ Wih1, const float* __restrict__ Whh1,
    float* __restrict__ wsf) {
  const int i = blockIdx.x * 256 + threadIdx.x;
  if (i < 278528) {  // PW0: 68 kb4-blocks, k<16 from Wih0, k>=16 from Whh0
    const int kb4 = i >> 12;
    const int j   = (i >> 2) & 1023;
    const int kk  = i & 3;
    const int k   = kb4 * 4 + kk;
    wsf[PW0_F + i] = (k < 16) ? Wih0[j * 16 + k] : Whh0[j * 256 + (k - 16)];
  }
  if (i < 262144) {  // PW1A/PW1B: 64 kb4-blocks over K=256
    const int kb4 = i >> 12;
    const int j   = (i >> 2) & 1023;
    const int kk  = i & 3;
    const int k   = kb4 * 4 + kk;
    wsf[PW1A_F + i] = Wih1[j * 256 + k];
    wsf[PW1B_F + i] = Whh1[j * 256 + k];
  }
}

__global__ __launch_bounds__(TPB) void lstm_main(
    const float* __restrict__ traj,
    const float* __restrict__ bih0, const float* __restrict__ bhh0,
    const float* __restrict__ bih1, const float* __restrict__ bhh1,
    const float* __restrict__ Wlin, const float* __restrict__ blin,
    float* __restrict__ out, float* __restrict__ wsf) {
  __shared__ float sh_s0[4 * 272];    // per row: x[16] | h0[256]  (wg-private)
  __shared__ float sh_h1[4 * 256];    // h1 state (wg-private)
  __shared__ float sh_g[4 * 1024];    // gate pre-activations
  __shared__ float sh_wlin[2048];     // Wlin [8][256]
  __shared__ float sh_b0[1024];       // bih0+bhh0
  __shared__ float sh_b1[1024];
  __shared__ float sh_o[32];          // out[:,g-8] for this wg's 4 rows
  __shared__ float sh_part[256];      // head partials
  __shared__ float sh_blin[8];

  const int tid  = threadIdx.x;
  const int wg   = blockIdx.x;
  const int slot = wg >> 3;           // pipeline slot 0..7 (window t: t&7==slot)
  const int rq   = wg & 7;            // row quarter: rows 4rq..4rq+3
  const int rowBase = rq * 4;
  const int j1 = tid, j2 = tid + 512; // this thread's two gate columns

  unsigned* ctrl = (unsigned*)wsf;
  const f32x4* W0  = (const f32x4*)(wsf + PW0_F);
  const f32x4* W1A = (const f32x4*)(wsf + PW1A_F);
  const f32x4* W1B = (const f32x4*)(wsf + PW1B_F);

  // one-time LDS init (iteration-invariant)
  ((f32x4*)sh_wlin)[tid] = ((const f32x4*)Wlin)[tid];
  sh_b0[tid]       = bih0[tid] + bhh0[tid];
  sh_b0[tid + 512] = bih0[tid + 512] + bhh0[tid + 512];
  sh_b1[tid]       = bih1[tid] + bhh1[tid];
  sh_b1[tid + 512] = bih1[tid + 512] + bhh1[tid + 512];
  if (tid < 8) sh_blin[tid] = blin[tid];

  float c0r[4], c1r[4];               // cell state (tid<256: unit u=tid)
  float acc[8];

  for (int g = 0; g < 127; ++g) {
    const int s = (g - slot) & 7;
    const int t = g - s;
    if (t < 0 || t > 119) continue;   // idle slot; no barriers to honor
    const bool fresh = (s == 0);
    const int tf = g - 7;             // == t when s==7
    const bool need_fb = (g >= 8);

    // ---- gate on out[:,g-8] (the ONLY cross-wg dependency) ----
    if (need_fb && tid == 0) {
      const unsigned need = (unsigned)(g - 7);
      while (rload(&ctrl[RDY_U(rq, slot)]) < need) __builtin_amdgcn_s_sleep(1);
    }
    __syncthreads();
    if (need_fb && tid < 32) {        // 4 rows x 8 dims of out[:,g-8]
      const int r = tid >> 3, o = tid & 7;
      sh_o[tid] = mall_load_f(out + (rowBase + r) * 960 + (g - 8) * 8 + o);
    }
    __syncthreads();

    // ---- stage x (16 dims per row) ----
    if (tid < 64) {
      const int r = tid >> 4, d = tid & 15;
      const int b = rowBase + r;
      float xv;
      if (t <= 7 && s < 8 - t) {
        xv = traj[b * 2048 + (t + s) * 16 + d];              // raw (g<8 only)
      } else if (d < 8) {
        const int ti = (t <= 7) ? (2 * t + s - 1) : (t + s);
        xv = traj[b * 2048 + ti * 16 + d];                   // ctrl half
      } else {
        xv = sh_o[r * 8 + (d - 8)];                          // fed-back preds
      }
      sh_s0[r * 272 + d] = xv;
    }
    if (fresh && tid < 256) {         // zero wg-private h state on window start
#pragma unroll
      for (int r = 0; r < 4; ++r) {
        sh_s0[r * 272 + 16 + tid] = 0.f;
        sh_h1[r * 256 + tid] = 0.f;
      }
    }
    __syncthreads();

    // ---- layer 0: gates = [x|h0] @ W0 + b0   (K=272) ----
#pragma unroll
    for (int r = 0; r < 4; ++r) { acc[r] = sh_b0[j1]; acc[4 + r] = sh_b0[j2]; }
#pragma unroll 2
    for (int kb = 0; kb < 68; ++kb) {
      const f32x4 w1 = W0[kb * 1024 + j1];
      const f32x4 w2 = W0[kb * 1024 + j2];
#pragma unroll
      for (int r = 0; r < 4; ++r) {
        const f32x4 in = *(const f32x4*)(sh_s0 + r * 272 + kb * 4);
        acc[r]     = fmaf(in.x, w1.x, acc[r]);
        acc[r]     = fmaf(in.y, w1.y, acc[r]);
        acc[r]     = fmaf(in.z, w1.z, acc[r]);
        acc[r]     = fmaf(in.w, w1.w, acc[r]);
        acc[4 + r] = fmaf(in.x, w2.x, acc[4 + r]);
        acc[4 + r] = fmaf(in.y, w2.y, acc[4 + r]);
        acc[4 + r] = fmaf(in.z, w2.z, acc[4 + r]);
        acc[4 + r] = fmaf(in.w, w2.w, acc[4 + r]);
      }
    }
#pragma unroll
    for (int r = 0; r < 4; ++r) {
      sh_g[r * 1024 + j1] = acc[r];
      sh_g[r * 1024 + j2] = acc[4 + r];
    }
    __syncthreads();

    // ---- LSTM update layer 0 (h0' overwrites h0 in place) ----
    if (tid < 256) {
      const int u = tid;
#pragma unroll
      for (int r = 0; r < 4; ++r) {
        const float iv = sh_g[r * 1024 + u];
        const float fv = sh_g[r * 1024 + 256 + u];
        const float gv = sh_g[r * 1024 + 512 + u];
        const float ov = sh_g[r * 1024 + 768 + u];
        const float cold = fresh ? 0.f : c0r[r];
        const float cn = sigf(fv) * cold + sigf(iv) * tanhfast(gv);
        c0r[r] = cn;
        sh_s0[r * 272 + 16 + u] = sigf(ov) * tanhfast(cn);
      }
    }
    __syncthreads();

    // ---- layer 1: gates = h0' @ Wih1 + h1 @ Whh1 + b1 ----
#pragma unroll
    for (int r = 0; r < 4; ++r) { acc[r] = sh_b1[j1]; acc[4 + r] = sh_b1[j2]; }
#pragma unroll 2
    for (int kb = 0; kb < 64; ++kb) {
      const f32x4 w1 = W1A[kb * 1024 + j1];
      const f32x4 w2 = W1A[kb * 1024 + j2];
#pragma unroll
      for (int r = 0; r < 4; ++r) {
        const f32x4 in = *(const f32x4*)(sh_s0 + r * 272 + 16 + kb * 4);
        acc[r]     = fmaf(in.x, w1.x, acc[r]);
        acc[r]     = fmaf(in.y, w1.y, acc[r]);
        acc[r]     = fmaf(in.z, w1.z, acc[r]);
        acc[r]     = fmaf(in.w, w1.w, acc[r]);
        acc[4 + r] = fmaf(in.x, w2.x, acc[4 + r]);
        acc[4 + r] = fmaf(in.y, w2.y, acc[4 + r]);
        acc[4 + r] = fmaf(in.z, w2.z, acc[4 + r]);
        acc[4 + r] = fmaf(in.w, w2.w, acc[4 + r]);
      }
    }
#pragma unroll 2
    for (int kb = 0; kb < 64; ++kb) {
      const f32x4 w1 = W1B[kb * 1024 + j1];
      const f32x4 w2 = W1B[kb * 1024 + j2];
#pragma unroll
      for (int r = 0; r < 4; ++r) {
        const f32x4 in = *(const f32x4*)(sh_h1 + r * 256 + kb * 4);
        acc[r]     = fmaf(in.x, w1.x, acc[r]);
        acc[r]     = fmaf(in.y, w1.y, acc[r]);
        acc[r]     = fmaf(in.z, w1.z, acc[r]);
        acc[r]     = fmaf(in.w, w1.w, acc[r]);
        acc[4 + r] = fmaf(in.x, w2.x, acc[4 + r]);
        acc[4 + r] = fmaf(in.y, w2.y, acc[4 + r]);
        acc[4 + r] = fmaf(in.z, w2.z, acc[4 + r]);
        acc[4 + r] = fmaf(in.w, w2.w, acc[4 + r]);
      }
    }
#pragma unroll
    for (int r = 0; r < 4; ++r) {
      sh_g[r * 1024 + j1] = acc[r];
      sh_g[r * 1024 + j2] = acc[4 + r];
    }
    __syncthreads();

    // ---- LSTM update layer 1 ----
    if (tid < 256) {
      const int u = tid;
#pragma unroll
      for (int r = 0; r < 4; ++r) {
        const float iv = sh_g[r * 1024 + u];
        const float fv = sh_g[r * 1024 + 256 + u];
        const float gv = sh_g[r * 1024 + 512 + u];
        const float ov = sh_g[r * 1024 + 768 + u];
        const float cold = fresh ? 0.f : c1r[r];
        const float cn = sigf(fv) * cold + sigf(iv) * tanhfast(gv);
        c1r[r] = cn;
        sh_h1[r * 256 + u] = sigf(ov) * tanhfast(cn);
      }
    }
    __syncthreads();

    // ---- head + out column + RDY (finishing slot only: s==7, t==tf) ----
    if (s == 7) {
      if (tid < 256) {  // partial dots: (r,o) x 8-way K-split
        const int r = tid >> 6, o = (tid >> 3) & 7, q = tid & 7;
        const float* hb = sh_h1 + r * 256 + q * 32;
        const float* wb = sh_wlin + o * 256 + q * 32;
        float sum = 0.f;
#pragma unroll 8
        for (int k = 0; k < 32; ++k) sum = fmaf(hb[k], wb[k], sum);
        sh_part[tid] = sum;
      }
      __syncthreads();
      if (tid < 32) {
        const int r = tid >> 3, o = tid & 7;
        const int b = rowBase + r;
        float pred = sh_blin[o];
#pragma unroll
        for (int q = 0; q < 8; ++q) pred += sh_part[r * 64 + o * 8 + q];
        const float base = (tf == 0) ? traj[b * 2048 + 7 * 16 + 8 + o]
                                     : sh_o[r * 8 + o];   // == out[:,tf-1]
        mall_store_f(out + b * 960 + tf * 8 + o, base + pred);
      }
      vmdrain();
      __syncthreads();   // out column at MALL before RDY posts
      if (tid < 8) rstore(&ctrl[RDY_U(rq, tid)], (unsigned)(tf + 1));

      // epilogue: window 119 final state (only slot 7 valid at g==126)
      if (g == 126 && tid < 256) {
        const int u = tid;
#pragma unroll
        for (int r = 0; r < 4; ++r) {
          const int b = rowBase + r;
          out[30720 + b * 256 + u] = sh_s0[r * 272 + 16 + u];  // h_n L0
          out[38912 + b * 256 + u] = sh_h1[r * 256 + u];       // h_n L1
          out[47104 + b * 256 + u] = c0r[r];                   // c_n L0
          out[55296 + b * 256 + u] = c1r[r];                   // c_n L1
        }
      }
    }
  }
}

extern "C" void kernel_launch(void* const* d_in, const int* in_sizes, int n_in,
                              void* d_out, int out_size, void* d_ws, size_t ws_size,
                              hipStream_t stream) {
  (void)in_sizes; (void)n_in; (void)out_size; (void)ws_size;
  const float* traj = (const float*)d_in[0];
  const float* Wih0 = (const float*)d_in[1];
  const float* Whh0 = (const float*)d_in[2];
  const float* bih0 = (const float*)d_in[3];
  const float* bhh0 = (const float*)d_in[4];
  const float* Wih1 = (const float*)d_in[5];
  const float* Whh1 = (const float*)d_in[6];
  const float* bih1 = (const float*)d_in[7];
  const float* bhh1 = (const float*)d_in[8];
  const float* Wlin = (const float*)d_in[9];
  const float* blin = (const float*)d_in[10];
  float* out = (float*)d_out;
  float* wsf = (float*)d_ws;

  hipMemsetAsync(d_ws, 0, CTRL_BYTES, stream);
  lstm_prep<<<1088, 256, 0, stream>>>(Wih0, Whh0, Wih1, Whh1, wsf);

  void* args[] = {(void*)&traj, (void*)&bih0, (void*)&bhh0, (void*)&bih1,
                  (void*)&bhh1, (void*)&Wlin, (void*)&blin, (void*)&out,
                  (void*)&wsf};
  hipLaunchCooperativeKernel((void*)lstm_main, dim3(NWG), dim3(TPB), args, 0,
                             stream);
}